// Round 7
// baseline (387.343 us; speedup 1.0000x reference)
//
#include <hip/hip_runtime.h>
#include <stdint.h>

#define NR 8192
#define DE 1024
#define DC 512
#define BIGF 9999999.0f
#define MARG 0.3f
#define NEGI -3.0e38f
#define POSI 3.0e38f

typedef __attribute__((ext_vector_type(8))) short bf16x8;
typedef __attribute__((ext_vector_type(4))) float f32x4;
typedef unsigned long long u64;

typedef __attribute__((address_space(3))) unsigned int lds_u32;
typedef const __attribute__((address_space(1))) unsigned int glb_u32;

static __device__ __forceinline__ void ld_g2l16(const void* g, void* l) {
    __builtin_amdgcn_global_load_lds((glb_u32*)g, (lds_u32*)l, 16, 0, 0);
}

// merge sorted pair (v1>=v2) with sorted pair (o1>=o2) -> top2 of union (with indices)
static __device__ __forceinline__ void merge_top2(float& v1, int& i1, float& v2, int& i2,
                                                  float o1, int oi1, float o2, int oi2) {
    bool a = o1 > v1;
    float hi = a ? o1 : v1;  int hii = a ? oi1 : i1;
    float lo = a ? v1 : o1;  int loi = a ? i1 : oi1;
    float s  = a ? o2 : v2;  int si  = a ? oi2 : i2;
    bool b = s > lo;
    v1 = hi; i1 = hii;
    v2 = b ? s : lo; i2 = b ? si : loi;
}

static __device__ __forceinline__ unsigned short f2bf(float x) {
    unsigned u = __float_as_uint(x);
    unsigned r = u + 0x7FFFu + ((u >> 16) & 1u);
    return (unsigned short)(r >> 16);
}

// ---------------- K1: emb -> bf16, sq[i] = ||emb_i||^2, class histogram ----------------
__global__ __launch_bounds__(256) void k_prep_emb(const float* __restrict__ emb,
                                                  const int* __restrict__ label,
                                                  short* __restrict__ embb,
                                                  float* __restrict__ sq,
                                                  int* __restrict__ cnt) {
    int row = blockIdx.x, tid = threadIdx.x;
    float4 v = ((const float4*)(emb + (size_t)row * DE))[tid];   // 1024/4 = 256 float4
    float s = v.x * v.x + v.y * v.y + v.z * v.z + v.w * v.w;
    ushort4 b;
    b.x = f2bf(v.x); b.y = f2bf(v.y); b.z = f2bf(v.z); b.w = f2bf(v.w);
    *(ushort4*)&embb[(size_t)row * DE + tid * 4] = b;
    for (int m = 1; m < 64; m <<= 1) s += __shfl_xor(s, m);
    __shared__ float red[4];
    if ((tid & 63) == 0) red[tid >> 6] = s;
    __syncthreads();
    if (tid == 0) {
        sq[row] = red[0] + red[1] + red[2] + red[3];
        atomicAdd(&cnt[label[row]], 1);
    }
}

// ---------------- K4: symmetric fused GEMM + row & column reductions ----------------
// Compact 1D grid of 544 active blocks: block L -> (bx, pnl) with pnl <= 4*bx+3.
// jt covers col-panels qp = 4*bx+jt with qp >= pnl (jt0 = max(0, pnl-4*bx)).
// Off-diagonal tiles also produce column-side reductions (dist symmetric; MFMA d2
// bit-identical across the diagonal). Column epilogue is ni-outer AND fenced with
// sched_barrier(0) per iteration: plain "#pragma unroll" alone let the pre-RA
// scheduler interleave all 8 ni states -> 160 MB/dispatch scratch spill (R5/R6).
__global__ __launch_bounds__(256, 2) void k_main(const short* __restrict__ embb,
                                                 const float* __restrict__ sq,
                                                 const int* __restrict__ label,
                                                 float* __restrict__ rV1, float* __restrict__ rV2,
                                                 unsigned* __restrict__ rI,
                                                 float* __restrict__ cV1g, float* __restrict__ cV2g,
                                                 unsigned* __restrict__ cIg,
                                                 unsigned* __restrict__ mnA, u64* __restrict__ kvA) {
    // unpack upper-triangular block index: cum(bx) = 2*bx^2 + 2*bx
    const int L = blockIdx.x;
    int bx = (int)((sqrtf((float)(1 + 2 * L)) - 1.0f) * 0.5f);
    while (2 * (bx + 1) * (bx + 1) + 2 * (bx + 1) <= L) ++bx;
    while (2 * bx * bx + 2 * bx > L) --bx;
    const int pnl = L - (2 * bx * bx + 2 * bx);
    const int d = pnl - bx * 4;
    const int jt0 = d > 0 ? d : 0;

    __shared__ __align__(16) short As[128 * 32];
    __shared__ __align__(16) short Bs[128 * 32];
    __shared__ float cbV1[4][128], cbV2[4][128];
    __shared__ unsigned cbI[4][128], cbMn[4][128], cbKv[4][128], cbKi[4][128];

    const int tid = threadIdx.x;
    const int lane = tid & 63;
    const int w = tid >> 6;
    const int q = lane >> 4, l15 = lane & 15;
    const int i0 = pnl * 128;

    // staging source swizzle: slot rr = tid>>2, c = tid&3 -> global chunk g
    const int srow = tid >> 2;
    const int g = (tid & 3) ^ ((tid >> 3) & 3);
    const short* gA = embb + (size_t)(i0 + srow) * DE + g * 8;
    const short* gB = embb + (size_t)(bx * 512 + jt0 * 128 + srow) * DE + g * 8;

    // fragment read swizzle
    const int pxor = q ^ ((l15 >> 1) & 3);

    // per-row reduction state: pp = mi*4 + r -> row = i0 + w*32 + (pp>>2)*16 + q*4 + (pp&3)
    float v1[8], v2[8], mnn[8], kvv[8], sqi[8];
    int i1a[8], i2a[8], kia[8], lia[8];
#pragma unroll
    for (int pp = 0; pp < 8; ++pp) {
        v1[pp] = NEGI; v2[pp] = NEGI; mnn[pp] = POSI; kvv[pp] = NEGI;
        i1a[pp] = 0; i2a[pp] = 0; kia[pp] = 0;
        int rowg = i0 + w * 32 + (pp >> 2) * 16 + q * 4 + (pp & 3);
        sqi[pp] = sq[rowg]; lia[pp] = label[rowg];
    }

    auto stage = [&](int koff, const short* gBb) {
        ld_g2l16(gA + koff, &As[(size_t)tid * 8]);
        ld_g2l16(gA + (size_t)64 * DE + koff, &As[(size_t)(tid + 256) * 8]);
        ld_g2l16(gBb + koff, &Bs[(size_t)tid * 8]);
        ld_g2l16(gBb + (size_t)64 * DE + koff, &Bs[(size_t)(tid + 256) * 8]);
    };

    stage(0, gB);   // prefetch (jt0, ks=0)

    for (int jt = jt0; jt < 4; ++jt) {
        const int j0 = bx * 512 + jt * 128;
        const bool diag = (j0 == i0);
        f32x4 acc[2][8];
#pragma unroll
        for (int mi = 0; mi < 2; ++mi)
#pragma unroll
            for (int ni = 0; ni < 8; ++ni) acc[mi][ni] = (f32x4){0.f, 0.f, 0.f, 0.f};

        for (int ks = 0; ks < 32; ++ks) {
            __syncthreads();          // staging visible (vmcnt drain)
            bf16x8 af[2], bfr[8];
#pragma unroll
            for (int mi = 0; mi < 2; ++mi)
                af[mi] = *(const bf16x8*)&As[(w * 32 + mi * 16 + l15) * 32 + pxor * 8];
#pragma unroll
            for (int ni = 0; ni < 8; ++ni)
                bfr[ni] = *(const bf16x8*)&Bs[(ni * 16 + l15) * 32 + pxor * 8];
#pragma unroll
            for (int mi = 0; mi < 2; ++mi)
#pragma unroll
                for (int ni = 0; ni < 8; ++ni)
                    acc[mi][ni] = __builtin_amdgcn_mfma_f32_16x16x32_bf16(af[mi], bfr[ni], acc[mi][ni], 0, 0, 0);
            __syncthreads();          // all reads done before next staging writes
            if (ks < 31) {
                stage((ks + 1) * 32, gB);
            } else if (jt < 3) {
                gB += (size_t)128 * DE;
                stage(0, gB);         // prefetch next jt; overlaps insert phase below
            }
        }

        // ---- epilogue for tile (pnl, j0/128): ni-outer, schedule-fenced ----
        __builtin_amdgcn_sched_barrier(0);   // keep epilogue out of the K-loop schedule
#pragma unroll
        for (int ni = 0; ni < 8; ++ni) {
            const int cg = j0 + ni * 16 + l15;
            const float sqjv = sq[cg];
            const int lbjv = label[cg];
            float cv1 = NEGI, cv2 = NEGI, cmn = POSI, ckv = NEGI;
            int ci1 = 0, ci2 = 0, cki = 0;
#pragma unroll
            for (int mi = 0; mi < 2; ++mi) {
#pragma unroll
                for (int r = 0; r < 4; ++r) {
                    const int pp = mi * 4 + r;
                    float d2 = fmaf(-2.0f, acc[mi][ni][r], sqi[pp] + sqjv);
                    d2 = fmaxf(d2, 1e-12f);
                    const bool same = (lia[pp] == lbjv);
                    const float kp = same ? d2 : NEGI;
                    const float kn = same ? NEGI : d2;
                    // row-side insert
                    bool c1 = kp > v1[pp], c2 = kp > v2[pp];
                    v2[pp] = c1 ? v1[pp] : (c2 ? kp : v2[pp]);
                    i2a[pp] = c1 ? i1a[pp] : (c2 ? cg : i2a[pp]);
                    v1[pp] = c1 ? kp : v1[pp];
                    i1a[pp] = c1 ? cg : i1a[pp];
                    mnn[pp] = fminf(mnn[pp], same ? POSI : d2);
                    bool ck = kn > kvv[pp];
                    kvv[pp] = ck ? kn : kvv[pp]; kia[pp] = ck ? cg : kia[pp];
                    // column-side insert (transposed contribution)
                    if (!diag) {
                        const int rowg = i0 + w * 32 + mi * 16 + q * 4 + r;
                        bool b1 = kp > cv1, b2 = kp > cv2;
                        cv2 = b1 ? cv1 : (b2 ? kp : cv2);
                        ci2 = b1 ? ci1 : (b2 ? rowg : ci2);
                        cv1 = b1 ? kp : cv1;
                        ci1 = b1 ? rowg : ci1;
                        cmn = fminf(cmn, same ? POSI : d2);
                        bool bk = kn > ckv;
                        ckv = bk ? kn : ckv; cki = bk ? rowg : cki;
                    }
                }
            }
            if (!diag) {
                // butterfly rows across q (xor 16,32), then stash per-wave result
                for (int m = 16; m <= 32; m <<= 1) {
                    float o1 = __shfl_xor(cv1, m); int oi1 = __shfl_xor(ci1, m);
                    float o2 = __shfl_xor(cv2, m); int oi2 = __shfl_xor(ci2, m);
                    merge_top2(cv1, ci1, cv2, ci2, o1, oi1, o2, oi2);
                    cmn = fminf(cmn, __shfl_xor(cmn, m));
                    float ok = __shfl_xor(ckv, m); int oki = __shfl_xor(cki, m);
                    bool ck = ok > ckv;
                    ckv = ck ? ok : ckv; cki = ck ? oki : cki;
                }
                if (q == 0) {
                    int cl = ni * 16 + l15;
                    cbV1[w][cl] = cv1; cbV2[w][cl] = cv2;
                    cbI[w][cl] = (unsigned)ci1 | ((unsigned)ci2 << 16);
                    cbMn[w][cl] = __float_as_uint(cmn);
                    cbKv[w][cl] = __float_as_uint(ckv);
                    cbKi[w][cl] = (unsigned)cki;
                }
            }
            __builtin_amdgcn_sched_barrier(0);   // one ni state live at a time
        }

        if (!diag) {
            __syncthreads();
            if (tid < 128) {
                unsigned I0 = cbI[0][tid];
                float V1 = cbV1[0][tid], V2 = cbV2[0][tid];
                int I1 = I0 & 0xFFFF, I2 = I0 >> 16;
                float Mn = __uint_as_float(cbMn[0][tid]);
                float Kv = __uint_as_float(cbKv[0][tid]);
                int Ki = cbKi[0][tid];
#pragma unroll
                for (int ww = 1; ww < 4; ++ww) {
                    unsigned Ix = cbI[ww][tid];
                    merge_top2(V1, I1, V2, I2, cbV1[ww][tid], Ix & 0xFFFF, cbV2[ww][tid], Ix >> 16);
                    Mn = fminf(Mn, __uint_as_float(cbMn[ww][tid]));
                    float ko = __uint_as_float(cbKv[ww][tid]);
                    if (ko > Kv) { Kv = ko; Ki = cbKi[ww][tid]; }
                }
                int col = j0 + tid;
                size_t cid = (size_t)col * 64 + pnl;
                cV1g[cid] = V1; cV2g[cid] = V2;
                cIg[cid] = (unsigned)I1 | ((unsigned)I2 << 16);
                atomicMin(&mnA[col], __float_as_uint(Mn));
                atomicMax(&kvA[col], ((u64)__float_as_uint(Kv) << 32) | (unsigned)Ki);
            }
        }
    }

    // row-side final butterfly over the 16 col-residues (l15), once per block
#pragma unroll
    for (int pp = 0; pp < 8; ++pp) {
        float lv1 = v1[pp], lv2 = v2[pp], lmn = mnn[pp], lkv = kvv[pp];
        int li1 = i1a[pp], li2 = i2a[pp], lki = kia[pp];
        for (int m = 1; m <= 8; m <<= 1) {
            float o1 = __shfl_xor(lv1, m); int oi1 = __shfl_xor(li1, m);
            float o2 = __shfl_xor(lv2, m); int oi2 = __shfl_xor(li2, m);
            merge_top2(lv1, li1, lv2, li2, o1, oi1, o2, oi2);
            lmn = fminf(lmn, __shfl_xor(lmn, m));
            float ok = __shfl_xor(lkv, m); int oki = __shfl_xor(lki, m);
            bool ck = ok > lkv;
            lkv = ck ? ok : lkv; lki = ck ? oki : lki;
        }
        if (l15 == 0) {
            int rowg = i0 + w * 32 + (pp >> 2) * 16 + q * 4 + (pp & 3);
            size_t idx = (size_t)rowg * 16 + bx;
            rV1[idx] = lv1; rV2[idx] = lv2;
            rI[idx] = (unsigned)li1 | ((unsigned)li2 << 16);
            atomicMin(&mnA[rowg], __float_as_uint(lmn));
            atomicMax(&kvA[rowg], ((u64)__float_as_uint(lkv) << 32) | (unsigned)lki);
        }
    }
}

// ---------------- K5: merge partials, decode, norms + alpha dots ----------------
// one wave per row. Valid slots for row r (panel P = r>>7):
//   row-side: chunks c in [P>>2, 16)  -> slot s in [0, 16-(P>>2))
//   col-side: contributing panels p' in [0, P) -> slot 16-(P>>2) + p'
// total <= 64, one slot per lane.
__global__ __launch_bounds__(256) void k_merge_alpha(const float* __restrict__ rV1, const float* __restrict__ rV2,
                                                     const unsigned* __restrict__ rI,
                                                     const float* __restrict__ cV1, const float* __restrict__ cV2,
                                                     const unsigned* __restrict__ cI,
                                                     const unsigned* __restrict__ mnA, const u64* __restrict__ kvA,
                                                     const int* __restrict__ label, const int* __restrict__ cnt,
                                                     const float* __restrict__ clot,
                                                     float* __restrict__ ap1, float* __restrict__ ap2,
                                                     float* __restrict__ an,
                                                     float* __restrict__ alpha1, float* __restrict__ alpha2) {
    int wid = threadIdx.x >> 6, lane = threadIdx.x & 63;
    int row = blockIdx.x * 4 + wid;
    const int P = row >> 7;
    const int cmin = P >> 2;
    const int nrow = 16 - cmin;
    const int total = nrow + P;

    float v1 = NEGI, v2 = NEGI;
    int i1 = 0, i2 = 0;
    if (lane < total) {
        float a, b; unsigned I;
        if (lane < nrow) {
            size_t id = (size_t)row * 16 + (cmin + lane);
            a = rV1[id]; b = rV2[id]; I = rI[id];
        } else {
            size_t id = (size_t)row * 64 + (lane - nrow);
            a = cV1[id]; b = cV2[id]; I = cI[id];
        }
        v1 = a; v2 = b; i1 = I & 0xFFFF; i2 = I >> 16;
    }
    for (int m = 1; m < 64; m <<= 1) {
        float o1 = __shfl_xor(v1, m); int oi1 = __shfl_xor(i1, m);
        float o2 = __shfl_xor(v2, m); int oi2 = __shfl_xor(i2, m);
        merge_top2(v1, i1, v2, i2, o1, oi1, o2, oi2);
    }

    float mn = __uint_as_float(mnA[row]);
    u64 kpack = kvA[row];
    float kv = __uint_as_float((unsigned)(kpack >> 32));
    int ki = (int)(kpack & 0xFFFFFFFFull);

    int cc = cnt[label[row]];
    float a1 = sqrtf(v1);
    int j1 = i1;
    float a2v; int j2;
    if (cc >= 2) {
        a2v = sqrtf(v2);
        j2 = i2;
    } else {
        // single-member class: ref's top-2 falls back to best (max-dist) negative - BIG
        a2v = sqrtf(kv) - BIGF;
        j2 = ki;
    }

    // alpha dots + norms: cos(row, j1), cos(row, j2)
    const float4* c4 = (const float4*)clot;
    float s1 = 0.f, s2 = 0.f, n0 = 0.f, n1 = 0.f, n2 = 0.f;
    for (int t = lane; t < DC / 4; t += 64) {
        float4 a = c4[(size_t)row * (DC / 4) + t];
        float4 b1 = c4[(size_t)j1 * (DC / 4) + t];
        float4 b2 = c4[(size_t)j2 * (DC / 4) + t];
        s1 += a.x * b1.x + a.y * b1.y + a.z * b1.z + a.w * b1.w;
        s2 += a.x * b2.x + a.y * b2.y + a.z * b2.z + a.w * b2.w;
        n0 += a.x * a.x + a.y * a.y + a.z * a.z + a.w * a.w;
        n1 += b1.x * b1.x + b1.y * b1.y + b1.z * b1.z + b1.w * b1.w;
        n2 += b2.x * b2.x + b2.y * b2.y + b2.z * b2.z + b2.w * b2.w;
    }
    for (int m = 1; m < 64; m <<= 1) {
        s1 += __shfl_xor(s1, m); s2 += __shfl_xor(s2, m);
        n0 += __shfl_xor(n0, m); n1 += __shfl_xor(n1, m); n2 += __shfl_xor(n2, m);
    }
    if (lane == 0) {
        ap1[row] = a1; ap2[row] = a2v; an[row] = sqrtf(mn);
        alpha1[row] = s1 / (sqrtf(n0) * sqrtf(n1));
        alpha2[row] = s2 / (sqrtf(n0) * sqrtf(n2));
    }
}

// ---------------- K7: final loss + prec ----------------
__global__ __launch_bounds__(256) void k_final(const float* __restrict__ ap1, const float* __restrict__ ap2,
                                               const float* __restrict__ an,
                                               const float* __restrict__ alpha1, const float* __restrict__ alpha2,
                                               float* __restrict__ out) {
    int tid = threadIdx.x;
    float sl11 = 0.f, sl13 = 0.f, sp = 0.f;
    for (int row = tid; row < NR; row += 256) {
        float a1 = alpha1[row], a2 = alpha2[row];
        float dap1 = ap1[row], dap2 = ap2[row], dan = an[row];
        float y = (a1 < a2) ? -1.f : 1.f;
        float ym = (a1 == a2) ? 0.f : 1.f;
        float x1 = dap2 * ym;
        float x2 = dap1 * ym + MARG * (a1 - a2 - y);
        sl11 += fmaxf(0.f, -y * (x1 - x2) + MARG);
        float ap1m = dap1 + MARG * (a1 - 1.f);
        sl13 += fmaxf(0.f, -(dan - ap1m) + MARG);
        sp += (dan > ap1m) ? 1.f : 0.f;
    }
    for (int m = 1; m < 64; m <<= 1) {
        sl11 += __shfl_xor(sl11, m);
        sl13 += __shfl_xor(sl13, m);
        sp += __shfl_xor(sp, m);
    }
    __shared__ float r11[4], r13[4], rp[4];
    if ((tid & 63) == 0) { r11[tid >> 6] = sl11; r13[tid >> 6] = sl13; rp[tid >> 6] = sp; }
    __syncthreads();
    if (tid == 0) {
        float t11 = r11[0] + r11[1] + r11[2] + r11[3];
        float t13 = r13[0] + r13[1] + r13[2] + r13[3];
        float tp = rp[0] + rp[1] + rp[2] + rp[3];
        out[0] = 0.1f * (t11 / (float)NR) + t13 / (float)NR;
        out[1] = tp / (float)NR;
    }
}

extern "C" void kernel_launch(void* const* d_in, const int* in_sizes, int n_in,
                              void* d_out, int out_size, void* d_ws, size_t ws_size,
                              hipStream_t stream) {
    const float* emb = (const float*)d_in[0];
    const int* label = (const int*)d_in[1];
    const float* clot = (const float*)d_in[2];
    float* out = (float*)d_out;

    char* ws = (char*)d_ws;
    size_t off = 0;
    auto alloc = [&](size_t bytes) -> char* {
        char* p = ws + off;
        off = (off + bytes + 255) & ~(size_t)255;
        return p;
    };
    short*    embb = (short*)alloc((size_t)NR * DE * 2);
    float*    sq   = (float*)alloc(NR * 4);
    int*      cnt  = (int*)alloc(512 * 4);
    float*    rV1  = (float*)alloc((size_t)NR * 16 * 4);
    float*    rV2  = (float*)alloc((size_t)NR * 16 * 4);
    unsigned* rI   = (unsigned*)alloc((size_t)NR * 16 * 4);
    float*    cV1  = (float*)alloc((size_t)NR * 64 * 4);
    float*    cV2  = (float*)alloc((size_t)NR * 64 * 4);
    unsigned* cI   = (unsigned*)alloc((size_t)NR * 64 * 4);
    unsigned* mnA  = (unsigned*)alloc((size_t)NR * 4);
    u64*      kvA  = (u64*)alloc((size_t)NR * 8);
    float*    ap1  = (float*)alloc(NR * 4);
    float*    ap2  = (float*)alloc(NR * 4);
    float*    an   = (float*)alloc(NR * 4);
    float*    al1  = (float*)alloc(NR * 4);
    float*    al2  = (float*)alloc(NR * 4);

    hipMemsetAsync(cnt, 0, 512 * 4, stream);
    hipMemsetAsync(mnA, 0xFF, (size_t)NR * 4, stream);     // uint-max: +inf for positive-float min
    hipMemsetAsync(kvA, 0, (size_t)NR * 8, stream);        // 0: -inf for positive-float max

    k_prep_emb<<<dim3(NR), dim3(256), 0, stream>>>(emb, label, embb, sq, cnt);
    k_main<<<dim3(544), dim3(256), 0, stream>>>(embb, sq, label,
                                                rV1, rV2, rI, cV1, cV2, cI, mnA, kvA);
    k_merge_alpha<<<dim3(NR / 4), dim3(256), 0, stream>>>(rV1, rV2, rI, cV1, cV2, cI, mnA, kvA,
                                                          label, cnt, clot,
                                                          ap1, ap2, an, al1, al2);
    k_final<<<dim3(1), dim3(256), 0, stream>>>(ap1, ap2, an, al1, al2, out);
}

// Round 8
// 250.863 us; speedup vs baseline: 1.5440x; 1.5440x over previous
//
#include <hip/hip_runtime.h>
#include <stdint.h>

#define NR 8192
#define DE 1024
#define DC 512
#define BIGF 9999999.0f
#define MARG 0.3f
#define NEGI -3.0e38f
#define POSI 3.0e38f

typedef __attribute__((ext_vector_type(8))) short bf16x8;
typedef __attribute__((ext_vector_type(4))) float f32x4;

typedef __attribute__((address_space(3))) unsigned int lds_u32;
typedef const __attribute__((address_space(1))) unsigned int glb_u32;

static __device__ __forceinline__ void ld_g2l16(const void* g, void* l) {
    __builtin_amdgcn_global_load_lds((glb_u32*)g, (lds_u32*)l, 16, 0, 0);
}

static __device__ __forceinline__ unsigned short f2bf(float x) {
    unsigned u = __float_as_uint(x);
    unsigned r = u + 0x7FFFu + ((u >> 16) & 1u);
    return (unsigned short)(r >> 16);
}

static __device__ __forceinline__ float b2f(short u) {
    return __uint_as_float(((unsigned)(unsigned short)u) << 16);
}

// ---------------- K1: emb -> bf16, sq[i] = ||emb_i||^2, class histogram ----------------
__global__ __launch_bounds__(256) void k_prep_emb(const float* __restrict__ emb,
                                                  const int* __restrict__ label,
                                                  short* __restrict__ embb,
                                                  float* __restrict__ sq,
                                                  int* __restrict__ cnt) {
    int row = blockIdx.x, tid = threadIdx.x;
    float4 v = ((const float4*)(emb + (size_t)row * DE))[tid];
    float s = v.x * v.x + v.y * v.y + v.z * v.z + v.w * v.w;
    ushort4 b;
    b.x = f2bf(v.x); b.y = f2bf(v.y); b.z = f2bf(v.z); b.w = f2bf(v.w);
    *(ushort4*)&embb[(size_t)row * DE + tid * 4] = b;
    for (int m = 1; m < 64; m <<= 1) s += __shfl_xor(s, m);
    __shared__ float red[4];
    if ((tid & 63) == 0) red[tid >> 6] = s;
    __syncthreads();
    if (tid == 0) {
        sq[row] = red[0] + red[1] + red[2] + red[3];
        atomicAdd(&cnt[label[row]], 1);
    }
}

// ---------------- K2: exclusive scan of class counts (512, single block) ----------------
__global__ __launch_bounds__(512) void k_scan(const int* __restrict__ cnt,
                                              int* __restrict__ clsOff) {
    __shared__ int s[512];
    int t = threadIdx.x;
    s[t] = cnt[t];
    __syncthreads();
    for (int d = 1; d < 512; d <<= 1) {
        int v = (t >= d) ? s[t - d] : 0;
        __syncthreads();
        s[t] += v;
        __syncthreads();
    }
    clsOff[t] = s[t] - cnt[t];
}

// ---------------- K3: scatter rows into class member lists ----------------
__global__ __launch_bounds__(256) void k_fill(const int* __restrict__ label,
                                              const int* __restrict__ clsOff,
                                              int* __restrict__ fill,
                                              int* __restrict__ list) {
    int i = blockIdx.x * 256 + threadIdx.x;
    int l = label[i];
    int p = atomicAdd(&fill[l], 1);
    list[clsOff[l] + p] = i;
}

// ---------------- K4: symmetric GEMM + min-of-negative row & column reductions ----------------
// 544 upper-triangular blocks: L -> (bx, pnl), pnl <= 4*bx+3; jt covers col-panels
// q = 4*bx+jt with q >= pnl. Negative side needs ONLY the min value (hard_n_idx is
// unused by the reference); positives/top-2 are recomputed exactly per class in k_pos.
// So all reduction state is one float per row/col -> no spill, no partial arrays,
// results go straight to atomicMin(mnA).
__global__ __launch_bounds__(256, 3) void k_main(const short* __restrict__ embb,
                                                 const float* __restrict__ sq,
                                                 const int* __restrict__ label,
                                                 unsigned* __restrict__ mnA) {
    const int L = blockIdx.x;
    int bx = (int)((sqrtf((float)(1 + 2 * L)) - 1.0f) * 0.5f);
    while (2 * (bx + 1) * (bx + 1) + 2 * (bx + 1) <= L) ++bx;
    while (2 * bx * bx + 2 * bx > L) --bx;
    const int pnl = L - (2 * bx * bx + 2 * bx);
    const int d = pnl - bx * 4;
    const int jt0 = d > 0 ? d : 0;

    __shared__ __align__(16) short As[128 * 32];
    __shared__ __align__(16) short Bs[128 * 32];

    const int tid = threadIdx.x;
    const int lane = tid & 63;
    const int w = tid >> 6;
    const int q = lane >> 4, l15 = lane & 15;
    const int i0 = pnl * 128;

    // staging source swizzle: slot rr = tid>>2, c = tid&3 -> global chunk g
    const int srow = tid >> 2;
    const int g = (tid & 3) ^ ((tid >> 3) & 3);
    const short* gA = embb + (size_t)(i0 + srow) * DE + g * 8;
    const short* gB = embb + (size_t)(bx * 512 + jt0 * 128 + srow) * DE + g * 8;

    // fragment read swizzle (conflict-free: 2 lanes/bank)
    const int pxor = q ^ ((l15 >> 1) & 3);

    // per-row state: min over negatives (value only), carried across all jt tiles
    float rmn[8], sqi[8];
    int lia[8];
#pragma unroll
    for (int pp = 0; pp < 8; ++pp) {
        rmn[pp] = POSI;
        int rowg = i0 + w * 32 + (pp >> 2) * 16 + q * 4 + (pp & 3);
        sqi[pp] = sq[rowg]; lia[pp] = label[rowg];
    }

    auto stage = [&](int koff, const short* gBb) {
        ld_g2l16(gA + koff, &As[(size_t)tid * 8]);
        ld_g2l16(gA + (size_t)64 * DE + koff, &As[(size_t)(tid + 256) * 8]);
        ld_g2l16(gBb + koff, &Bs[(size_t)tid * 8]);
        ld_g2l16(gBb + (size_t)64 * DE + koff, &Bs[(size_t)(tid + 256) * 8]);
    };

    stage(0, gB);   // prefetch (jt0, ks=0)

    for (int jt = jt0; jt < 4; ++jt) {
        const int j0 = bx * 512 + jt * 128;
        f32x4 acc[2][8];
#pragma unroll
        for (int mi = 0; mi < 2; ++mi)
#pragma unroll
            for (int ni = 0; ni < 8; ++ni) acc[mi][ni] = (f32x4){0.f, 0.f, 0.f, 0.f};

        for (int ks = 0; ks < 32; ++ks) {
            __syncthreads();          // staging visible (vmcnt drain)
            bf16x8 af[2], bfr[8];
#pragma unroll
            for (int mi = 0; mi < 2; ++mi)
                af[mi] = *(const bf16x8*)&As[(w * 32 + mi * 16 + l15) * 32 + pxor * 8];
#pragma unroll
            for (int ni = 0; ni < 8; ++ni)
                bfr[ni] = *(const bf16x8*)&Bs[(ni * 16 + l15) * 32 + pxor * 8];
#pragma unroll
            for (int mi = 0; mi < 2; ++mi)
#pragma unroll
                for (int ni = 0; ni < 8; ++ni)
                    acc[mi][ni] = __builtin_amdgcn_mfma_f32_16x16x32_bf16(af[mi], bfr[ni], acc[mi][ni], 0, 0, 0);
            __syncthreads();          // all reads done before next staging writes
            if (ks < 31) {
                stage((ks + 1) * 32, gB);
            } else if (jt < 3) {
                gB += (size_t)128 * DE;
                stage(0, gB);         // prefetch next jt; overlaps epilogue below
            }
        }

        // ---- slim epilogue: row-min (registers) + col-min (butterfly + atomic) ----
        // Col-side on the diagonal tile double-counts the same pairs -> harmless for min.
#pragma unroll
        for (int ni = 0; ni < 8; ++ni) {
            const int cg = j0 + ni * 16 + l15;
            const float sqjv = sq[cg];
            const int lbjv = label[cg];
            float cmn = POSI;
#pragma unroll
            for (int pp = 0; pp < 8; ++pp) {
                float d2 = fmaf(-2.0f, acc[pp >> 2][ni][pp & 3], sqi[pp] + sqjv);
                d2 = fmaxf(d2, 1e-12f);
                float dn = (lia[pp] == lbjv) ? POSI : d2;
                rmn[pp] = fminf(rmn[pp], dn);
                cmn = fminf(cmn, dn);
            }
            cmn = fminf(cmn, __shfl_xor(cmn, 16));
            cmn = fminf(cmn, __shfl_xor(cmn, 32));
            if (q == 0) atomicMin(&mnA[cg], __float_as_uint(cmn));
        }
    }

    // row-side final butterfly over the 16 col-residues, once per block
#pragma unroll
    for (int pp = 0; pp < 8; ++pp) {
        float m0 = rmn[pp];
        for (int s = 1; s <= 8; s <<= 1) m0 = fminf(m0, __shfl_xor(m0, s));
        if (l15 == 0) {
            int rowg = i0 + w * 32 + (pp >> 2) * 16 + q * 4 + (pp & 3);
            atomicMin(&mnA[rowg], __float_as_uint(m0));
        }
    }
}

// ---------------- K5: exact per-row positives (top-2 over classmates) + alphas ----------------
// one wave per row. ~16 classmates: exact d2 via bf16 dot, exact top-2 with indices and
// jax top_k tie-break (lower index). Self is in the list: d(i,i)=clip floor (ranks last).
// cc==1 fallback: ref's top-2 second value = max-neg - BIG; full scan (expected never hit).
__global__ __launch_bounds__(256) void k_pos(const short* __restrict__ embb,
                                             const float* __restrict__ sq,
                                             const float* __restrict__ clot,
                                             const int* __restrict__ label,
                                             const int* __restrict__ cnt,
                                             const int* __restrict__ clsOff,
                                             const int* __restrict__ clsList,
                                             const unsigned* __restrict__ mnA,
                                             float* __restrict__ ap1, float* __restrict__ ap2,
                                             float* __restrict__ an,
                                             float* __restrict__ alpha1, float* __restrict__ alpha2) {
    int wid = threadIdx.x >> 6, lane = threadIdx.x & 63;
    int row = blockIdx.x * 4 + wid;
    int lb = label[row];
    int cc = cnt[lb], off = clsOff[lb];
    float sqiv = sq[row];

    // row chunk: lane covers dims [lane*16, lane*16+16)
    const bf16x8* rp = (const bf16x8*)(embb + (size_t)row * DE + lane * 16);
    bf16x8 ra = rp[0], rb = rp[1];
    float rf[16];
#pragma unroll
    for (int t = 0; t < 8; ++t) { rf[t] = b2f(ra[t]); rf[8 + t] = b2f(rb[t]); }

    float v1 = NEGI, v2 = NEGI;
    int i1 = 0, i2 = 0;
    for (int m = 0; m < cc; ++m) {
        int j = clsList[off + m];
        float d2;
        if (j == row) {
            d2 = 1e-12f;
        } else {
            const bf16x8* jp = (const bf16x8*)(embb + (size_t)j * DE + lane * 16);
            bf16x8 ja = jp[0], jb = jp[1];
            float s = 0.f;
#pragma unroll
            for (int t = 0; t < 8; ++t) s = fmaf(rf[t], b2f(ja[t]), s);
#pragma unroll
            for (int t = 0; t < 8; ++t) s = fmaf(rf[8 + t], b2f(jb[t]), s);
            for (int mm = 1; mm < 64; mm <<= 1) s += __shfl_xor(s, mm);
            d2 = fmaxf(fmaf(-2.0f, s, sqiv + sq[j]), 1e-12f);
        }
        bool t1 = (d2 > v1) || (d2 == v1 && j < i1);
        bool t2 = (d2 > v2) || (d2 == v2 && j < i2);
        v2 = t1 ? v1 : (t2 ? d2 : v2);
        i2 = t1 ? i1 : (t2 ? j : i2);
        v1 = t1 ? d2 : v1;
        i1 = t1 ? j : i1;
    }

    float a1 = sqrtf(v1);
    int j1 = i1;
    float a2v; int j2;
    if (cc >= 2) {
        a2v = sqrtf(v2);
        j2 = i2;
    } else {
        // singleton class: ref falls back to best (max-dist) negative - BIG
        float kv = NEGI; int ki = 0;
        for (int c = lane; c < NR; c += 64) {
            if (label[c] == lb) continue;
            const bf16x8* cp = (const bf16x8*)(embb + (size_t)c * DE);
            float s = 0.f;
            for (int t = 0; t < 128; ++t) {
                bf16x8 cv = cp[t];
#pragma unroll
                for (int u = 0; u < 8; ++u) s = fmaf(b2f(ra[0]) * 0.f + 1.f, 0.f, s);  // placeholder avoided below
            }
            // recompute properly (serial full-row dot)
            s = 0.f;
            const short* crow = embb + (size_t)c * DE;
            const short* rrow = embb + (size_t)row * DE;
            for (int t = 0; t < DE; ++t) s = fmaf(b2f(rrow[t]), b2f(crow[t]), s);
            float d2c = fmaxf(fmaf(-2.0f, s, sqiv + sq[c]), 1e-12f);
            bool tk = (d2c > kv) || (d2c == kv && c < ki);
            kv = tk ? d2c : kv; ki = tk ? c : ki;
        }
        for (int mm = 1; mm < 64; mm <<= 1) {
            float ov = __shfl_xor(kv, mm); int oi = __shfl_xor(ki, mm);
            bool tk = (ov > kv) || (ov == kv && oi < ki);
            kv = tk ? ov : kv; ki = tk ? oi : ki;
        }
        a2v = sqrtf(kv) - BIGF;
        j2 = ki;
    }

    // alpha dots + norms over clot
    const float4* c4 = (const float4*)clot;
    float s1 = 0.f, s2 = 0.f, n0 = 0.f, n1 = 0.f, n2 = 0.f;
    for (int t = lane; t < DC / 4; t += 64) {
        float4 a = c4[(size_t)row * (DC / 4) + t];
        float4 b1 = c4[(size_t)j1 * (DC / 4) + t];
        float4 b2 = c4[(size_t)j2 * (DC / 4) + t];
        s1 += a.x * b1.x + a.y * b1.y + a.z * b1.z + a.w * b1.w;
        s2 += a.x * b2.x + a.y * b2.y + a.z * b2.z + a.w * b2.w;
        n0 += a.x * a.x + a.y * a.y + a.z * a.z + a.w * a.w;
        n1 += b1.x * b1.x + b1.y * b1.y + b1.z * b1.z + b1.w * b1.w;
        n2 += b2.x * b2.x + b2.y * b2.y + b2.z * b2.z + b2.w * b2.w;
    }
    for (int mm = 1; mm < 64; mm <<= 1) {
        s1 += __shfl_xor(s1, mm); s2 += __shfl_xor(s2, mm);
        n0 += __shfl_xor(n0, mm); n1 += __shfl_xor(n1, mm); n2 += __shfl_xor(n2, mm);
    }
    if (lane == 0) {
        ap1[row] = a1; ap2[row] = a2v;
        an[row] = sqrtf(__uint_as_float(mnA[row]));
        alpha1[row] = s1 / (sqrtf(n0) * sqrtf(n1));
        alpha2[row] = s2 / (sqrtf(n0) * sqrtf(n2));
    }
}

// ---------------- K7: final loss + prec ----------------
__global__ __launch_bounds__(256) void k_final(const float* __restrict__ ap1, const float* __restrict__ ap2,
                                               const float* __restrict__ an,
                                               const float* __restrict__ alpha1, const float* __restrict__ alpha2,
                                               float* __restrict__ out) {
    int tid = threadIdx.x;
    float sl11 = 0.f, sl13 = 0.f, sp = 0.f;
    for (int row = tid; row < NR; row += 256) {
        float a1 = alpha1[row], a2 = alpha2[row];
        float dap1 = ap1[row], dap2 = ap2[row], dan = an[row];
        float y = (a1 < a2) ? -1.f : 1.f;
        float ym = (a1 == a2) ? 0.f : 1.f;
        float x1 = dap2 * ym;
        float x2 = dap1 * ym + MARG * (a1 - a2 - y);
        sl11 += fmaxf(0.f, -y * (x1 - x2) + MARG);
        float ap1m = dap1 + MARG * (a1 - 1.f);
        sl13 += fmaxf(0.f, -(dan - ap1m) + MARG);
        sp += (dan > ap1m) ? 1.f : 0.f;
    }
    for (int m = 1; m < 64; m <<= 1) {
        sl11 += __shfl_xor(sl11, m);
        sl13 += __shfl_xor(sl13, m);
        sp += __shfl_xor(sp, m);
    }
    __shared__ float r11[4], r13[4], rp[4];
    if ((tid & 63) == 0) { r11[tid >> 6] = sl11; r13[tid >> 6] = sl13; rp[tid >> 6] = sp; }
    __syncthreads();
    if (tid == 0) {
        float t11 = r11[0] + r11[1] + r11[2] + r11[3];
        float t13 = r13[0] + r13[1] + r13[2] + r13[3];
        float tp = rp[0] + rp[1] + rp[2] + rp[3];
        out[0] = 0.1f * (t11 / (float)NR) + t13 / (float)NR;
        out[1] = tp / (float)NR;
    }
}

extern "C" void kernel_launch(void* const* d_in, const int* in_sizes, int n_in,
                              void* d_out, int out_size, void* d_ws, size_t ws_size,
                              hipStream_t stream) {
    const float* emb = (const float*)d_in[0];
    const int* label = (const int*)d_in[1];
    const float* clot = (const float*)d_in[2];
    float* out = (float*)d_out;

    char* ws = (char*)d_ws;
    size_t off = 0;
    auto alloc = [&](size_t bytes) -> char* {
        char* p = ws + off;
        off = (off + bytes + 255) & ~(size_t)255;
        return p;
    };
    short*    embb = (short*)alloc((size_t)NR * DE * 2);
    float*    sq   = (float*)alloc(NR * 4);
    int*      cnt  = (int*)alloc(512 * 4);
    int*      cOff = (int*)alloc(512 * 4);
    int*      fill = (int*)alloc(512 * 4);
    int*      list = (int*)alloc(NR * 4);
    unsigned* mnA  = (unsigned*)alloc((size_t)NR * 4);
    float*    ap1  = (float*)alloc(NR * 4);
    float*    ap2  = (float*)alloc(NR * 4);
    float*    an   = (float*)alloc(NR * 4);
    float*    al1  = (float*)alloc(NR * 4);
    float*    al2  = (float*)alloc(NR * 4);

    hipMemsetAsync(cnt, 0, 512 * 4, stream);
    hipMemsetAsync(fill, 0, 512 * 4, stream);
    hipMemsetAsync(mnA, 0xFF, (size_t)NR * 4, stream);   // large bits: +inf for positive-float min

    k_prep_emb<<<dim3(NR), dim3(256), 0, stream>>>(emb, label, embb, sq, cnt);
    k_scan<<<dim3(1), dim3(512), 0, stream>>>(cnt, cOff);
    k_fill<<<dim3(NR / 256), dim3(256), 0, stream>>>(label, cOff, fill, list);
    k_main<<<dim3(544), dim3(256), 0, stream>>>(embb, sq, label, mnA);
    k_pos<<<dim3(NR / 4), dim3(256), 0, stream>>>(embb, sq, clot, label, cnt, cOff, list,
                                                  mnA, ap1, ap2, an, al1, al2);
    k_final<<<dim3(1), dim3(256), 0, stream>>>(ap1, ap2, an, al1, al2, out);
}